// Round 9
// baseline (351.274 us; speedup 1.0000x reference)
//
#include <hip/hip_runtime.h>

typedef unsigned short ushort_t;
typedef __attribute__((ext_vector_type(8))) short short8;
typedef __attribute__((ext_vector_type(4))) short short4v;
typedef __attribute__((ext_vector_type(4))) float f32x4;

#define LOG2E 1.44269504088896f

// async global->LDS, 16B per lane. LDS dest must be wave-uniform base + lane*16.
__device__ __forceinline__ void async16(const void* g, void* l) {
  __builtin_amdgcn_global_load_lds(
      (const __attribute__((address_space(1))) void*)g,
      (__attribute__((address_space(3))) void*)l, 16, 0, 0);
}

__device__ __forceinline__ ushort_t f2bf(float f) {
  union { float f; unsigned u; } x; x.f = f;
  unsigned u = x.u;
  u += 0x7fffu + ((u >> 16) & 1u);
  return (ushort_t)(u >> 16);
}

__device__ __forceinline__ float bf2f(ushort_t w) {
  union { unsigned u; float f; } x; x.u = ((unsigned)w) << 16;
  return x.f;
}

// ---------------- split ingest: fp32 -> (hi, lo) bf16 ----------------
__global__ __launch_bounds__(256) void split8(const float* __restrict__ src,
                                              ushort_t* __restrict__ hi,
                                              ushort_t* __restrict__ lo, int n8) {
  int i = blockIdx.x * 256 + threadIdx.x;
  if (i >= n8) return;
  const f32x4* s = (const f32x4*)src;
  f32x4 a = s[i * 2], b = s[i * 2 + 1];
  short8 oh, ol;
  #pragma unroll
  for (int j = 0; j < 4; j++) {
    ushort_t h = f2bf(a[j]); oh[j] = (short)h; ol[j] = (short)f2bf(a[j] - bf2f(h));
    h = f2bf(b[j]); oh[j + 4] = (short)h; ol[j + 4] = (short)f2bf(b[j] - bf2f(h));
  }
  ((short8*)hi)[i] = oh;
  ((short8*)lo)[i] = ol;
}

// ------- weight transpose+split: src fp32 [K][Nn] -> dstT hi/lo bf16 [Nn][K] -------
__global__ __launch_bounds__(256) void transpose_split(const float* __restrict__ src,
                                                       ushort_t* __restrict__ dh,
                                                       ushort_t* __restrict__ dl,
                                                       int K, int Nn) {
  __shared__ float tile[32][33];
  int bx = blockIdx.x * 32;  // Nn dim
  int by = blockIdx.y * 32;  // K dim
  int tx = threadIdx.x, ty = threadIdx.y;  // (32, 8)
  #pragma unroll
  for (int i = 0; i < 32; i += 8)
    tile[ty + i][tx] = src[(size_t)(by + ty + i) * Nn + bx + tx];
  __syncthreads();
  #pragma unroll
  for (int i = 0; i < 32; i += 8) {
    float v = tile[tx][ty + i];
    ushort_t h = f2bf(v);
    size_t idx = (size_t)(bx + ty + i) * K + by + tx;
    dh[idx] = h;
    dl[idx] = f2bf(v - bf2f(h));
  }
}

// ---- split GEMM: C = (Ah+Al)[M][K] @ (Bh+Bl)[Nn][K]^T, 3-product bf16x3 ----
// BM=128, BN=TN*32. 4 waves (2x2); wave tile = 64 x (TN*16).
template<int EPI, int TN>
__global__ __launch_bounds__(256) void gemm3_bt(const ushort_t* __restrict__ Ah,
                                                const ushort_t* __restrict__ Al,
                                                const ushort_t* __restrict__ Bh,
                                                const ushort_t* __restrict__ Bl,
                                                ushort_t* __restrict__ o_hi,
                                                ushort_t* __restrict__ o_lo,
                                                ushort_t* __restrict__ o_vt,
                                                float* __restrict__ outf,
                                                int K, int ldo) {
  constexpr int BN = TN * 32;
  __shared__ __align__(16) ushort_t Ash[128 * 32];
  __shared__ __align__(16) ushort_t Asl[128 * 32];
  __shared__ __align__(16) ushort_t Bsh[BN * 32];
  __shared__ __align__(16) ushort_t Bsl[BN * 32];
  const int tid = threadIdx.x;
  const int wave = tid >> 6, lane = tid & 63;
  const int wm = (wave >> 1) * 64, wn = (wave & 1) * (TN * 16);
  const int m0 = blockIdx.y * 128, n0 = blockIdx.x * BN;
  const int lrow = lane & 15, lq = lane >> 4;

  f32x4 acc[4][TN];
  const f32x4 z = {0.f, 0.f, 0.f, 0.f};
  #pragma unroll
  for (int i = 0; i < 4; i++)
    #pragma unroll
    for (int j = 0; j < TN; j++) acc[i][j] = z;

  for (int k0 = 0; k0 < K; k0 += 32) {
    __syncthreads();
    #pragma unroll
    for (int i = 0; i < 2; i++) {        // A tile: 128 rows
      int g = i * 256 + tid;
      int r = g >> 2, kc = g & 3;
      size_t ga = (size_t)(m0 + r) * K + k0 + kc * 8;
      async16(&Ah[ga], &Ash[g * 8]);
      async16(&Al[ga], &Asl[g * 8]);
    }
    #pragma unroll
    for (int i = 0; i < BN / 64; i++) {  // B tile: BN rows
      int g = i * 256 + tid;
      int r = g >> 2, kc = g & 3;
      size_t gb = (size_t)(n0 + r) * K + k0 + kc * 8;
      async16(&Bh[gb], &Bsh[g * 8]);
      async16(&Bl[gb], &Bsl[g * 8]);
    }
    __syncthreads();  // drains vmcnt(0): all tiles landed

    short8 afh[4], bfr[TN];
    #pragma unroll
    for (int t = 0; t < 4; t++)
      afh[t] = *(const short8*)&Ash[(wm + t * 16 + lrow) * 32 + lq * 8];
    #pragma unroll
    for (int t = 0; t < TN; t++)
      bfr[t] = *(const short8*)&Bsh[(wn + t * 16 + lrow) * 32 + lq * 8];
    #pragma unroll
    for (int ti = 0; ti < 4; ti++)
      #pragma unroll
      for (int tj = 0; tj < TN; tj++)
        acc[ti][tj] = __builtin_amdgcn_mfma_f32_16x16x32_bf16(afh[ti], bfr[tj], acc[ti][tj], 0, 0, 0);

    {
      short8 afl[4];
      #pragma unroll
      for (int t = 0; t < 4; t++)
        afl[t] = *(const short8*)&Asl[(wm + t * 16 + lrow) * 32 + lq * 8];
      #pragma unroll
      for (int ti = 0; ti < 4; ti++)
        #pragma unroll
        for (int tj = 0; tj < TN; tj++)
          acc[ti][tj] = __builtin_amdgcn_mfma_f32_16x16x32_bf16(afl[ti], bfr[tj], acc[ti][tj], 0, 0, 0);
    }
    #pragma unroll
    for (int t = 0; t < TN; t++)
      bfr[t] = *(const short8*)&Bsl[(wn + t * 16 + lrow) * 32 + lq * 8];
    #pragma unroll
    for (int ti = 0; ti < 4; ti++)
      #pragma unroll
      for (int tj = 0; tj < TN; tj++)
        acc[ti][tj] = __builtin_amdgcn_mfma_f32_16x16x32_bf16(afh[ti], bfr[tj], acc[ti][tj], 0, 0, 0);
  }

  // epilogue
  #pragma unroll
  for (int ti = 0; ti < 4; ti++) {
    #pragma unroll
    for (int tj = 0; tj < TN; tj++) {
      int row0 = m0 + wm + ti * 16 + lq * 4;
      int col = n0 + wn + tj * 16 + lrow;
      #pragma unroll
      for (int r = 0; r < 4; r++) {
        int m = row0 + r;
        float fv = acc[ti][tj][r];
        if (EPI == 0) {
          size_t idx = (size_t)((m >> 10) * 8 + (col >> 6)) * 65536 + (m & 1023) * 64 + (col & 63);
          ushort_t h = f2bf(fv);
          o_hi[idx] = h;
          o_lo[idx] = f2bf(fv - bf2f(h));
        } else if (EPI == 1) {
          if (col < 512) {
            size_t idx = (size_t)((m >> 10) * 8 + (col >> 6)) * 65536 + (m & 1023) * 64 + (col & 63);
            ushort_t h = f2bf(fv);
            o_hi[idx] = h;
            o_lo[idx] = f2bf(fv - bf2f(h));
          } else {
            int cc = col - 512;
            o_vt[(size_t)(((m >> 10) * 8 + (cc >> 6)) * 64 + (cc & 63)) * 1024 + (m & 1023)] = f2bf(fv);
          }
        } else {
          outf[(size_t)m * ldo + col] = fv;   // fp32 final output
        }
      }
    }
  }
}

// ---------------- flash attention v2: in-register softmax, b64 LDS ----------------
// grid = B*H*(N/128) = 512 blocks, 256 threads. Wave w owns 32 Q rows.
// LS=68 ushorts/row; P^T stored as packed dwords (uniform types -> no TBAA hazard).
__global__ __launch_bounds__(256) void flash_attn(const ushort_t* __restrict__ qh,
                                                  const ushort_t* __restrict__ ql,
                                                  const ushort_t* __restrict__ kh,
                                                  const ushort_t* __restrict__ kl,
                                                  const ushort_t* __restrict__ vtb,
                                                  ushort_t* __restrict__ obh,
                                                  ushort_t* __restrict__ obl) {
  constexpr int LS = 68;
  constexpr int PTW = 17;                             // P^T dword stride (34 ushorts)
  __shared__ __align__(16) ushort_t Ksh[64 * LS];
  __shared__ __align__(16) ushort_t Ksl[64 * LS];
  __shared__ __align__(16) ushort_t VTs[64 * LS];
  __shared__ __align__(16) unsigned Pt[4][64 * PTW];  // per wave: P^T [col][row/2] packed

  const int tid = threadIdx.x;
  const int wave = tid >> 6, lane = tid & 63;
  const int bh = blockIdx.x >> 3, qt = blockIdx.x & 7;
  const int lrow = lane & 15, lq = lane >> 4;
  unsigned* Ptw = &Pt[wave][0];

  const ushort_t* Qh = qh + (size_t)bh * 65536;
  const ushort_t* Ql = ql + (size_t)bh * 65536;
  const ushort_t* Kph = kh + (size_t)bh * 65536;
  const ushort_t* Kpl = kl + (size_t)bh * 65536;
  const ushort_t* VT = vtb + (size_t)bh * 65536;

  const int qrow0 = qt * 128 + wave * 32;

  short8 qfh[2][2], qfl[2][2];
  #pragma unroll
  for (int mt = 0; mt < 2; mt++)
    #pragma unroll
    for (int s = 0; s < 2; s++) {
      size_t idx = (size_t)(qrow0 + mt * 16 + lrow) * 64 + s * 32 + lq * 8;
      qfh[mt][s] = *(const short8*)&Qh[idx];
      qfl[mt][s] = *(const short8*)&Ql[idx];
    }

  const f32x4 z = {0.f, 0.f, 0.f, 0.f};
  f32x4 oacc[2][4];
  #pragma unroll
  for (int mt = 0; mt < 2; mt++)
    #pragma unroll
    for (int dt = 0; dt < 4; dt++) oacc[mt][dt] = z;

  f32x4 m_i[2], l_i[2];
  #pragma unroll
  for (int mt = 0; mt < 2; mt++) {
    m_i[mt] = (f32x4){-1e30f, -1e30f, -1e30f, -1e30f};
    l_i[mt] = z;
  }

  for (int kt = 0; kt < 16; kt++) {
    // global loads first (overlap previous iteration's compute)
    short8 skh[2], skl[2], sv[2];
    #pragma unroll
    for (int i = 0; i < 2; i++) {
      int g = i * 256 + tid;      // 0..511
      int rw = g >> 3, ch = g & 7;
      size_t kidx = (size_t)(kt * 64 + rw) * 64 + ch * 8;
      skh[i] = *(const short8*)&Kph[kidx];
      skl[i] = *(const short8*)&Kpl[kidx];
      sv[i]  = *(const short8*)&VT[(size_t)rw * 1024 + kt * 64 + ch * 8];
    }
    __syncthreads();  // all waves done reading previous K/V tiles
    #pragma unroll
    for (int i = 0; i < 2; i++) {
      int g = i * 256 + tid;
      int rw = g >> 3, ch = g & 7;
      int l = rw * LS + ch * 8;
      *(short4v*)&Ksh[l] = (short4v){skh[i][0], skh[i][1], skh[i][2], skh[i][3]};
      *(short4v*)&Ksh[l + 4] = (short4v){skh[i][4], skh[i][5], skh[i][6], skh[i][7]};
      *(short4v*)&Ksl[l] = (short4v){skl[i][0], skl[i][1], skl[i][2], skl[i][3]};
      *(short4v*)&Ksl[l + 4] = (short4v){skl[i][4], skl[i][5], skl[i][6], skl[i][7]};
      *(short4v*)&VTs[l] = (short4v){sv[i][0], sv[i][1], sv[i][2], sv[i][3]};
      *(short4v*)&VTs[l + 4] = (short4v){sv[i][4], sv[i][5], sv[i][6], sv[i][7]};
    }
    __syncthreads();  // tiles in LDS

    // S = Q @ K^T with bf16x3: qh*kh + ql*kh + qh*kl
    f32x4 sacc[2][4];
    #pragma unroll
    for (int mt = 0; mt < 2; mt++)
      #pragma unroll
      for (int nt = 0; nt < 4; nt++) sacc[mt][nt] = z;
    #pragma unroll
    for (int s = 0; s < 2; s++) {
      short8 bfr[4];
      #pragma unroll
      for (int nt = 0; nt < 4; nt++) {
        const ushort_t* p = &Ksh[(nt * 16 + lrow) * LS + s * 32 + lq * 8];
        short4v a = *(const short4v*)p, b = *(const short4v*)(p + 4);
        bfr[nt] = (short8){a[0], a[1], a[2], a[3], b[0], b[1], b[2], b[3]};
      }
      #pragma unroll
      for (int mt = 0; mt < 2; mt++)
        #pragma unroll
        for (int nt = 0; nt < 4; nt++) {
          sacc[mt][nt] = __builtin_amdgcn_mfma_f32_16x16x32_bf16(qfh[mt][s], bfr[nt], sacc[mt][nt], 0, 0, 0);
          sacc[mt][nt] = __builtin_amdgcn_mfma_f32_16x16x32_bf16(qfl[mt][s], bfr[nt], sacc[mt][nt], 0, 0, 0);
        }
      #pragma unroll
      for (int nt = 0; nt < 4; nt++) {
        const ushort_t* p = &Ksl[(nt * 16 + lrow) * LS + s * 32 + lq * 8];
        short4v a = *(const short4v*)p, b = *(const short4v*)(p + 4);
        bfr[nt] = (short8){a[0], a[1], a[2], a[3], b[0], b[1], b[2], b[3]};
      }
      #pragma unroll
      for (int mt = 0; mt < 2; mt++)
        #pragma unroll
        for (int nt = 0; nt < 4; nt++)
          sacc[mt][nt] = __builtin_amdgcn_mfma_f32_16x16x32_bf16(qfh[mt][s], bfr[nt], sacc[mt][nt], 0, 0, 0);
    }

    // ---- in-register online softmax ----
    // C-layout: lane (lrow,lq) holds S[row=16mt+4lq+e][col=16nt+lrow].
    f32x4 rmax[2], rsum[2], mnew[2], alpha[2];
    #pragma unroll
    for (int mt = 0; mt < 2; mt++) {
      f32x4 r = sacc[mt][0];
      #pragma unroll
      for (int nt = 1; nt < 4; nt++)
        #pragma unroll
        for (int e = 0; e < 4; e++) r[e] = fmaxf(r[e], sacc[mt][nt][e]);
      rmax[mt] = r;
    }
    #pragma unroll
    for (int msk = 1; msk <= 8; msk <<= 1)
      #pragma unroll
      for (int mt = 0; mt < 2; mt++)
        #pragma unroll
        for (int e = 0; e < 4; e++)
          rmax[mt][e] = fmaxf(rmax[mt][e], __shfl_xor(rmax[mt][e], msk));
    #pragma unroll
    for (int mt = 0; mt < 2; mt++) {
      #pragma unroll
      for (int e = 0; e < 4; e++) {
        mnew[mt][e] = fmaxf(m_i[mt][e], rmax[mt][e]);
        alpha[mt][e] = exp2f((m_i[mt][e] - mnew[mt][e]) * LOG2E);
      }
      rsum[mt] = z;
    }
    // P = exp(S - mnew), accumulate row sums, write packed P^T dwords
    #pragma unroll
    for (int mt = 0; mt < 2; mt++)
      #pragma unroll
      for (int nt = 0; nt < 4; nt++) {
        f32x4 p;
        #pragma unroll
        for (int e = 0; e < 4; e++) {
          p[e] = exp2f((sacc[mt][nt][e] - mnew[mt][e]) * LOG2E);
          rsum[mt][e] += p[e];
        }
        unsigned w0 = (unsigned)f2bf(p[0]) | ((unsigned)f2bf(p[1]) << 16);
        unsigned w1 = (unsigned)f2bf(p[2]) | ((unsigned)f2bf(p[3]) << 16);
        int base = (nt * 16 + lrow) * PTW + mt * 8 + lq * 2;  // dword index
        Ptw[base] = w0;
        Ptw[base + 1] = w1;
      }
    #pragma unroll
    for (int msk = 1; msk <= 8; msk <<= 1)
      #pragma unroll
      for (int mt = 0; mt < 2; mt++)
        #pragma unroll
        for (int e = 0; e < 4; e++)
          rsum[mt][e] += __shfl_xor(rsum[mt][e], msk);
    #pragma unroll
    for (int mt = 0; mt < 2; mt++) {
      #pragma unroll
      for (int e = 0; e < 4; e++)
        l_i[mt][e] = l_i[mt][e] * alpha[mt][e] + rsum[mt][e];
      m_i[mt] = mnew[mt];
    }

    // rescale O by alpha
    #pragma unroll
    for (int mt = 0; mt < 2; mt++)
      #pragma unroll
      for (int dt = 0; dt < 4; dt++)
        #pragma unroll
        for (int e = 0; e < 4; e++) oacc[mt][dt][e] *= alpha[mt][e];

    // O += P @ V  (P A-frag from packed P^T dwords; wave-private, same-type accesses)
    #pragma unroll
    for (int s = 0; s < 2; s++) {
      short8 pf[2], vf[4];
      #pragma unroll
      for (int mt = 0; mt < 2; mt++) {
        unsigned tw[8];
        #pragma unroll
        for (int j = 0; j < 8; j++)
          tw[j] = Ptw[(s * 32 + lq * 8 + j) * PTW + mt * 8 + (lrow >> 1)];
        int sh = (lrow & 1) * 16;
        #pragma unroll
        for (int j = 0; j < 8; j++)
          pf[mt][j] = (short)((tw[j] >> sh) & 0xffff);
      }
      #pragma unroll
      for (int dt = 0; dt < 4; dt++) {
        const ushort_t* p = &VTs[(dt * 16 + lrow) * LS + s * 32 + lq * 8];
        short4v a = *(const short4v*)p, b = *(const short4v*)(p + 4);
        vf[dt] = (short8){a[0], a[1], a[2], a[3], b[0], b[1], b[2], b[3]};
      }
      #pragma unroll
      for (int mt = 0; mt < 2; mt++)
        #pragma unroll
        for (int dt = 0; dt < 4; dt++)
          oacc[mt][dt] = __builtin_amdgcn_mfma_f32_16x16x32_bf16(pf[mt], vf[dt], oacc[mt][dt], 0, 0, 0);
    }
  }

  // finalize: divide by l, split to hi/lo, write [B][N][H*D]
  const int b = bh >> 3, h = bh & 7;
  #pragma unroll
  for (int mt = 0; mt < 2; mt++)
    #pragma unroll
    for (int dt = 0; dt < 4; dt++)
      #pragma unroll
      for (int e = 0; e < 4; e++) {
        int n = qrow0 + mt * 16 + lq * 4 + e;
        int d = dt * 16 + lrow;
        float f = oacc[mt][dt][e] / l_i[mt][e];
        size_t idx = (size_t)(b * 1024 + n) * 512 + h * 64 + d;
        ushort_t hi = f2bf(f);
        obh[idx] = hi;
        obl[idx] = f2bf(f - bf2f(hi));
      }
}

// ---------------- launcher ----------------
extern "C" void kernel_launch(void* const* d_in, const int* in_sizes, int n_in,
                              void* d_out, int out_size, void* d_ws, size_t ws_size,
                              hipStream_t stream) {
  const float* cur = (const float*)d_in[0];   // [8,1024,512] fp32
  const float* hid = (const float*)d_in[1];   // [8,1024,512] fp32
  const float* Wq  = (const float*)d_in[2];   // [512,512]
  const float* Wkv = (const float*)d_in[3];   // [512,1024]
  const float* Wo  = (const float*)d_in[4];   // [512,512]

  ushort_t* ws = (ushort_t*)d_ws;
  ushort_t* Ah = ws;                    // 4,194,304  (hid split; reused: cur split; aout hi)
  ushort_t* Al = Ah + 4194304;          // 4,194,304  (… aout lo)
  ushort_t* kh = Al + 4194304;          // 4,194,304
  ushort_t* kl = kh + 4194304;          // 4,194,304
  ushort_t* vt = kl + 4194304;          // 4,194,304
  ushort_t* qhb = vt + 4194304;         // 4,194,304
  ushort_t* qlb = qhb + 4194304;        // 4,194,304
  ushort_t* WqTh = qlb + 4194304;       // 262,144
  ushort_t* WqTl = WqTh + 262144;       // 262,144
  ushort_t* WkvTh = WqTl + 262144;      // 524,288
  ushort_t* WkvTl = WkvTh + 524288;     // 524,288
  ushort_t* WoTh = WkvTl + 524288;      // 262,144
  ushort_t* WoTl = WoTh + 262144;       // 262,144

  dim3 tb(32, 8);
  transpose_split<<<dim3(16, 16), tb, 0, stream>>>(Wq, WqTh, WqTl, 512, 512);
  transpose_split<<<dim3(32, 16), tb, 0, stream>>>(Wkv, WkvTh, WkvTl, 512, 1024);
  transpose_split<<<dim3(16, 16), tb, 0, stream>>>(Wo, WoTh, WoTl, 512, 512);

  // kv projection (BN=128): 512 blocks
  split8<<<2048, 256, 0, stream>>>(hid, Ah, Al, 4194304 / 8);
  gemm3_bt<1, 4><<<dim3(8, 64), 256, 0, stream>>>(Ah, Al, WkvTh, WkvTl,
                                                  kh, kl, vt, (float*)nullptr, 512, 0);
  // q projection (BN=128): 256 blocks
  split8<<<2048, 256, 0, stream>>>(cur, Ah, Al, 4194304 / 8);
  gemm3_bt<0, 4><<<dim3(4, 64), 256, 0, stream>>>(Ah, Al, WqTh, WqTl,
                                                  qhb, qlb, (ushort_t*)nullptr, (float*)nullptr, 512, 0);
  // attention (A-region reused for aout hi/lo)
  flash_attn<<<512, 256, 0, stream>>>(qhb, qlb, kh, kl, vt, Ah, Al);
  // output projection (BN=128) -> fp32 d_out: 256 blocks
  gemm3_bt<2, 4><<<dim3(4, 64), 256, 0, stream>>>(Ah, Al, WoTh, WoTl,
                                                  (ushort_t*)nullptr, (ushort_t*)nullptr,
                                                  (ushort_t*)nullptr, (float*)d_out, 512, 512);
}

// Round 10
// 262.175 us; speedup vs baseline: 1.3398x; 1.3398x over previous
//
#include <hip/hip_runtime.h>

typedef unsigned short ushort_t;
typedef __attribute__((ext_vector_type(8))) short short8;
typedef __attribute__((ext_vector_type(4))) short short4v;
typedef __attribute__((ext_vector_type(4))) float f32x4;
typedef __attribute__((ext_vector_type(2))) unsigned uint2v;
typedef __attribute__((ext_vector_type(4))) unsigned uint4v;

#define LOG2E 1.44269504088896f

// async global->LDS, 16B per lane. LDS dest must be wave-uniform base + lane*16.
__device__ __forceinline__ void async16(const void* g, void* l) {
  __builtin_amdgcn_global_load_lds(
      (const __attribute__((address_space(1))) void*)g,
      (__attribute__((address_space(3))) void*)l, 16, 0, 0);
}

__device__ __forceinline__ ushort_t f2bf(float f) {
  union { float f; unsigned u; } x; x.f = f;
  unsigned u = x.u;
  u += 0x7fffu + ((u >> 16) & 1u);
  return (ushort_t)(u >> 16);
}

__device__ __forceinline__ float bf2f(ushort_t w) {
  union { unsigned u; float f; } x; x.u = ((unsigned)w) << 16;
  return x.f;
}

__device__ __forceinline__ short8 u4s8(uint4v u) { union { uint4v a; short8 b; } c; c.a = u; return c.b; }
__device__ __forceinline__ uint4v s8u4(short8 s) { union { short8 a; uint4v b; } c; c.a = s; return c.b; }
__device__ __forceinline__ unsigned fu(float f) { union { float a; unsigned b; } c; c.a = f; return c.b; }

// ---------------- split ingest: fp32 -> (hi, lo) bf16 ----------------
__global__ __launch_bounds__(256) void split8(const float* __restrict__ src,
                                              ushort_t* __restrict__ hi,
                                              ushort_t* __restrict__ lo, int n8) {
  int i = blockIdx.x * 256 + threadIdx.x;
  if (i >= n8) return;
  const f32x4* s = (const f32x4*)src;
  f32x4 a = s[i * 2], b = s[i * 2 + 1];
  short8 oh, ol;
  #pragma unroll
  for (int j = 0; j < 4; j++) {
    ushort_t h = f2bf(a[j]); oh[j] = (short)h; ol[j] = (short)f2bf(a[j] - bf2f(h));
    h = f2bf(b[j]); oh[j + 4] = (short)h; ol[j + 4] = (short)f2bf(b[j] - bf2f(h));
  }
  ((short8*)hi)[i] = oh;
  ((short8*)lo)[i] = ol;
}

// ------- weight transpose+split: src fp32 [K][Nn] -> dstT hi/lo bf16 [Nn][K] -------
__global__ __launch_bounds__(256) void transpose_split(const float* __restrict__ src,
                                                       ushort_t* __restrict__ dh,
                                                       ushort_t* __restrict__ dl,
                                                       int K, int Nn) {
  __shared__ float tile[32][33];
  int bx = blockIdx.x * 32;  // Nn dim
  int by = blockIdx.y * 32;  // K dim
  int tx = threadIdx.x, ty = threadIdx.y;  // (32, 8)
  #pragma unroll
  for (int i = 0; i < 32; i += 8)
    tile[ty + i][tx] = src[(size_t)(by + ty + i) * Nn + bx + tx];
  __syncthreads();
  #pragma unroll
  for (int i = 0; i < 32; i += 8) {
    float v = tile[tx][ty + i];
    ushort_t h = f2bf(v);
    size_t idx = (size_t)(bx + ty + i) * K + by + tx;
    dh[idx] = h;
    dl[idx] = f2bf(v - bf2f(h));
  }
}

// ---- split GEMM: C = (Ah+Al)[M][K] @ (Bh+Bl)[Nn][K]^T, 3-product bf16x3 ----
// BM=128, BN=TN*32. 4 waves (2x2); wave tile = 64 x (TN*16).
template<int EPI, int TN>
__global__ __launch_bounds__(256) void gemm3_bt(const ushort_t* __restrict__ Ah,
                                                const ushort_t* __restrict__ Al,
                                                const ushort_t* __restrict__ Bh,
                                                const ushort_t* __restrict__ Bl,
                                                ushort_t* __restrict__ o_hi,
                                                ushort_t* __restrict__ o_lo,
                                                ushort_t* __restrict__ o_vt,
                                                float* __restrict__ outf,
                                                int K, int ldo) {
  constexpr int BN = TN * 32;
  __shared__ __align__(16) ushort_t Ash[128 * 32];
  __shared__ __align__(16) ushort_t Asl[128 * 32];
  __shared__ __align__(16) ushort_t Bsh[BN * 32];
  __shared__ __align__(16) ushort_t Bsl[BN * 32];
  const int tid = threadIdx.x;
  const int wave = tid >> 6, lane = tid & 63;
  const int wm = (wave >> 1) * 64, wn = (wave & 1) * (TN * 16);
  const int m0 = blockIdx.y * 128, n0 = blockIdx.x * BN;
  const int lrow = lane & 15, lq = lane >> 4;

  f32x4 acc[4][TN];
  const f32x4 z = {0.f, 0.f, 0.f, 0.f};
  #pragma unroll
  for (int i = 0; i < 4; i++)
    #pragma unroll
    for (int j = 0; j < TN; j++) acc[i][j] = z;

  for (int k0 = 0; k0 < K; k0 += 32) {
    __syncthreads();
    #pragma unroll
    for (int i = 0; i < 2; i++) {        // A tile: 128 rows
      int g = i * 256 + tid;
      int r = g >> 2, kc = g & 3;
      size_t ga = (size_t)(m0 + r) * K + k0 + kc * 8;
      async16(&Ah[ga], &Ash[g * 8]);
      async16(&Al[ga], &Asl[g * 8]);
    }
    #pragma unroll
    for (int i = 0; i < BN / 64; i++) {  // B tile: BN rows
      int g = i * 256 + tid;
      int r = g >> 2, kc = g & 3;
      size_t gb = (size_t)(n0 + r) * K + k0 + kc * 8;
      async16(&Bh[gb], &Bsh[g * 8]);
      async16(&Bl[gb], &Bsl[g * 8]);
    }
    __syncthreads();  // drains vmcnt(0): all tiles landed

    short8 afh[4], bfr[TN];
    #pragma unroll
    for (int t = 0; t < 4; t++)
      afh[t] = *(const short8*)&Ash[(wm + t * 16 + lrow) * 32 + lq * 8];
    #pragma unroll
    for (int t = 0; t < TN; t++)
      bfr[t] = *(const short8*)&Bsh[(wn + t * 16 + lrow) * 32 + lq * 8];
    #pragma unroll
    for (int ti = 0; ti < 4; ti++)
      #pragma unroll
      for (int tj = 0; tj < TN; tj++)
        acc[ti][tj] = __builtin_amdgcn_mfma_f32_16x16x32_bf16(afh[ti], bfr[tj], acc[ti][tj], 0, 0, 0);

    {
      short8 afl[4];
      #pragma unroll
      for (int t = 0; t < 4; t++)
        afl[t] = *(const short8*)&Asl[(wm + t * 16 + lrow) * 32 + lq * 8];
      #pragma unroll
      for (int ti = 0; ti < 4; ti++)
        #pragma unroll
        for (int tj = 0; tj < TN; tj++)
          acc[ti][tj] = __builtin_amdgcn_mfma_f32_16x16x32_bf16(afl[ti], bfr[tj], acc[ti][tj], 0, 0, 0);
    }
    #pragma unroll
    for (int t = 0; t < TN; t++)
      bfr[t] = *(const short8*)&Bsl[(wn + t * 16 + lrow) * 32 + lq * 8];
    #pragma unroll
    for (int ti = 0; ti < 4; ti++)
      #pragma unroll
      for (int tj = 0; tj < TN; tj++)
        acc[ti][tj] = __builtin_amdgcn_mfma_f32_16x16x32_bf16(afh[ti], bfr[tj], acc[ti][tj], 0, 0, 0);
  }

  // epilogue
  #pragma unroll
  for (int ti = 0; ti < 4; ti++) {
    #pragma unroll
    for (int tj = 0; tj < TN; tj++) {
      int row0 = m0 + wm + ti * 16 + lq * 4;
      int col = n0 + wn + tj * 16 + lrow;
      #pragma unroll
      for (int r = 0; r < 4; r++) {
        int m = row0 + r;
        float fv = acc[ti][tj][r];
        if (EPI == 0) {
          size_t idx = (size_t)((m >> 10) * 8 + (col >> 6)) * 65536 + (m & 1023) * 64 + (col & 63);
          ushort_t h = f2bf(fv);
          o_hi[idx] = h;
          o_lo[idx] = f2bf(fv - bf2f(h));
        } else if (EPI == 1) {
          if (col < 512) {
            size_t idx = (size_t)((m >> 10) * 8 + (col >> 6)) * 65536 + (m & 1023) * 64 + (col & 63);
            ushort_t h = f2bf(fv);
            o_hi[idx] = h;
            o_lo[idx] = f2bf(fv - bf2f(h));
          } else {
            int cc = col - 512;
            o_vt[(size_t)(((m >> 10) * 8 + (cc >> 6)) * 64 + (cc & 63)) * 1024 + (m & 1023)] = f2bf(fv);
          }
        } else {
          outf[(size_t)m * ldo + col] = fv;   // fp32 final output
        }
      }
    }
  }
}

// ---------------- flash attention v3: LDS softmax round-trip, all-uniform banks ----
// grid = B*H*(N/128) = 512 blocks, 256 threads. Wave w owns 32 Q rows.
// K/V: dword stride 34/row (b64 slots uniform). Sw (S^T f32): stride 36 (b128/b32 ok).
// Pw (P rows, packed bf16 dwords): stride 36. All LDS accesses same-typed; only the
// two K/V-tile barriers remain (intra-wave LDS dependencies ordered by compiler).
__global__ __launch_bounds__(256) void flash_attn(const ushort_t* __restrict__ qh,
                                                  const ushort_t* __restrict__ ql,
                                                  const ushort_t* __restrict__ kh,
                                                  const ushort_t* __restrict__ kl,
                                                  const ushort_t* __restrict__ vtb,
                                                  ushort_t* __restrict__ obh,
                                                  ushort_t* __restrict__ obl) {
  constexpr int KW = 34;   // K/V row stride (dwords)
  constexpr int SWS = 36;  // Sw row stride (dwords)
  constexpr int PWS = 36;  // Pw row stride (dwords)
  __shared__ __align__(16) unsigned Ksh[64 * KW];
  __shared__ __align__(16) unsigned Ksl[64 * KW];
  __shared__ __align__(16) unsigned VTs[64 * KW];
  __shared__ __align__(16) float Sw[4][64 * SWS];     // per wave: S^T [col][row]
  __shared__ __align__(16) unsigned Pw[4][32 * PWS];  // per wave: P [row][col/2]

  const int tid = threadIdx.x;
  const int wave = tid >> 6, lane = tid & 63;
  const int bh = blockIdx.x >> 3, qt = blockIdx.x & 7;
  const int lrow = lane & 15, lq = lane >> 4;

  const ushort_t* Qh = qh + (size_t)bh * 65536;
  const ushort_t* Ql = ql + (size_t)bh * 65536;
  const ushort_t* Kph = kh + (size_t)bh * 65536;
  const ushort_t* Kpl = kl + (size_t)bh * 65536;
  const ushort_t* VT = vtb + (size_t)bh * 65536;

  const int qrow0 = qt * 128 + wave * 32;

  short8 qfh[2][2], qfl[2][2];
  #pragma unroll
  for (int mt = 0; mt < 2; mt++)
    #pragma unroll
    for (int s = 0; s < 2; s++) {
      size_t idx = (size_t)(qrow0 + mt * 16 + lrow) * 64 + s * 32 + lq * 8;
      qfh[mt][s] = *(const short8*)&Qh[idx];
      qfl[mt][s] = *(const short8*)&Ql[idx];
    }

  const f32x4 z = {0.f, 0.f, 0.f, 0.f};
  f32x4 oacc[2][4];
  #pragma unroll
  for (int mt = 0; mt < 2; mt++)
    #pragma unroll
    for (int dt = 0; dt < 4; dt++) oacc[mt][dt] = z;

  float m_i = -1e30f, l_i = 0.f;          // per row-owner lane (r = lane>>1)
  const int r = lane >> 1, hlf = lane & 1;

  for (int kt = 0; kt < 16; kt++) {
    // global prefetch into VGPRs (overlaps previous iteration's compute)
    short8 skh[2], skl[2], sv[2];
    #pragma unroll
    for (int i = 0; i < 2; i++) {
      int g = i * 256 + tid;      // 0..511
      int rw = g >> 3, ch = g & 7;
      size_t kidx = (size_t)(kt * 64 + rw) * 64 + ch * 8;
      skh[i] = *(const short8*)&Kph[kidx];
      skl[i] = *(const short8*)&Kpl[kidx];
      sv[i]  = *(const short8*)&VT[(size_t)rw * 1024 + kt * 64 + ch * 8];
    }
    __syncthreads();  // all waves done reading previous K/V tiles
    #pragma unroll
    for (int i = 0; i < 2; i++) {
      int g = i * 256 + tid;
      int rw = g >> 3, ch = g & 7;
      int l = rw * KW + ch * 4;           // dword offset
      uint4v a = s8u4(skh[i]);
      *(uint2v*)&Ksh[l] = (uint2v){a.x, a.y};
      *(uint2v*)&Ksh[l + 2] = (uint2v){a.z, a.w};
      a = s8u4(skl[i]);
      *(uint2v*)&Ksl[l] = (uint2v){a.x, a.y};
      *(uint2v*)&Ksl[l + 2] = (uint2v){a.z, a.w};
      a = s8u4(sv[i]);
      *(uint2v*)&VTs[l] = (uint2v){a.x, a.y};
      *(uint2v*)&VTs[l + 2] = (uint2v){a.z, a.w};
    }
    __syncthreads();  // tiles in LDS

    // S = Q @ K^T with bf16x3: qh*kh + ql*kh + qh*kl
    f32x4 sacc[2][4];
    #pragma unroll
    for (int mt = 0; mt < 2; mt++)
      #pragma unroll
      for (int nt = 0; nt < 4; nt++) sacc[mt][nt] = z;
    #pragma unroll
    for (int s = 0; s < 2; s++) {
      short8 bfr[4];
      #pragma unroll
      for (int nt = 0; nt < 4; nt++) {
        int base = (nt * 16 + lrow) * KW + s * 16 + lq * 4;
        uint2v a = *(const uint2v*)&Ksh[base];
        uint2v b = *(const uint2v*)&Ksh[base + 2];
        bfr[nt] = u4s8((uint4v){a.x, a.y, b.x, b.y});
      }
      #pragma unroll
      for (int mt = 0; mt < 2; mt++)
        #pragma unroll
        for (int nt = 0; nt < 4; nt++) {
          sacc[mt][nt] = __builtin_amdgcn_mfma_f32_16x16x32_bf16(qfh[mt][s], bfr[nt], sacc[mt][nt], 0, 0, 0);
          sacc[mt][nt] = __builtin_amdgcn_mfma_f32_16x16x32_bf16(qfl[mt][s], bfr[nt], sacc[mt][nt], 0, 0, 0);
        }
      #pragma unroll
      for (int nt = 0; nt < 4; nt++) {
        int base = (nt * 16 + lrow) * KW + s * 16 + lq * 4;
        uint2v a = *(const uint2v*)&Ksl[base];
        uint2v b = *(const uint2v*)&Ksl[base + 2];
        bfr[nt] = u4s8((uint4v){a.x, a.y, b.x, b.y});
      }
      #pragma unroll
      for (int mt = 0; mt < 2; mt++)
        #pragma unroll
        for (int nt = 0; nt < 4; nt++)
          sacc[mt][nt] = __builtin_amdgcn_mfma_f32_16x16x32_bf16(qfh[mt][s], bfr[nt], sacc[mt][nt], 0, 0, 0);
    }

    // store S^T (C-layout: col = 16nt+lrow, rows = 16mt+4lq+e) — b128, uniform slots
    #pragma unroll
    for (int mt = 0; mt < 2; mt++)
      #pragma unroll
      for (int nt = 0; nt < 4; nt++)
        *(f32x4*)&Sw[wave][(nt * 16 + lrow) * SWS + mt * 16 + lq * 4] = sacc[mt][nt];

    // online softmax by row-owner lane pairs (2r, 2r+1), 32 cols each
    float vals[32];
    float mx = -1e30f;
    #pragma unroll
    for (int j = 0; j < 32; j++) {
      vals[j] = Sw[wave][(hlf * 32 + j) * SWS + r];
      mx = fmaxf(mx, vals[j]);
    }
    mx = fmaxf(mx, __shfl_xor(mx, 1));
    float mnew = fmaxf(m_i, mx);
    float alpha = exp2f((m_i - mnew) * LOG2E);
    float sum = 0.f;
    #pragma unroll
    for (int j8 = 0; j8 < 4; j8++) {
      uint4v pk;
      #pragma unroll
      for (int q = 0; q < 4; q++) {
        float p0 = exp2f((vals[j8 * 8 + 2 * q] - mnew) * LOG2E);
        float p1 = exp2f((vals[j8 * 8 + 2 * q + 1] - mnew) * LOG2E);
        sum += p0 + p1;
        // truncate-to-bf16 pack: [hi16(p1) | hi16(p0)] in one v_perm
        pk[q] = __builtin_amdgcn_perm(fu(p1), fu(p0), 0x07060302u);
      }
      *(uint4v*)&Pw[wave][r * PWS + hlf * 16 + j8 * 4] = pk;
    }
    sum += __shfl_xor(sum, 1);
    l_i = l_i * alpha + sum;
    m_i = mnew;

    // alpha broadcast: consumer (C-layout row 16mt+4lq+e) <- owner lane 2*row
    f32x4 al[2];
    #pragma unroll
    for (int mt = 0; mt < 2; mt++)
      #pragma unroll
      for (int e = 0; e < 4; e++)
        al[mt][e] = __shfl(alpha, (mt * 16 + lq * 4 + e) * 2);
    #pragma unroll
    for (int mt = 0; mt < 2; mt++)
      #pragma unroll
      for (int dt = 0; dt < 4; dt++)
        #pragma unroll
        for (int e = 0; e < 4; e++) oacc[mt][dt][e] *= al[mt][e];

    // O += P @ V  (P A-frag: b128 from row-major Pw; V B-frag: b64 pairs)
    #pragma unroll
    for (int s = 0; s < 2; s++) {
      short8 pf[2], vf[4];
      #pragma unroll
      for (int mt = 0; mt < 2; mt++)
        pf[mt] = u4s8(*(const uint4v*)&Pw[wave][(mt * 16 + lrow) * PWS + s * 16 + lq * 4]);
      #pragma unroll
      for (int dt = 0; dt < 4; dt++) {
        int base = (dt * 16 + lrow) * KW + s * 16 + lq * 4;
        uint2v a = *(const uint2v*)&VTs[base];
        uint2v b = *(const uint2v*)&VTs[base + 2];
        vf[dt] = u4s8((uint4v){a.x, a.y, b.x, b.y});
      }
      #pragma unroll
      for (int mt = 0; mt < 2; mt++)
        #pragma unroll
        for (int dt = 0; dt < 4; dt++)
          oacc[mt][dt] = __builtin_amdgcn_mfma_f32_16x16x32_bf16(pf[mt], vf[dt], oacc[mt][dt], 0, 0, 0);
    }
  }

  // finalize: l broadcast via shuffle, divide, split hi/lo, write [B][N][H*D]
  const int b = bh >> 3, h = bh & 7;
  #pragma unroll
  for (int mt = 0; mt < 2; mt++) {
    f32x4 li;
    #pragma unroll
    for (int e = 0; e < 4; e++)
      li[e] = __shfl(l_i, (mt * 16 + lq * 4 + e) * 2);
    #pragma unroll
    for (int dt = 0; dt < 4; dt++)
      #pragma unroll
      for (int e = 0; e < 4; e++) {
        int n = qrow0 + mt * 16 + lq * 4 + e;
        int d = dt * 16 + lrow;
        float f = oacc[mt][dt][e] / li[e];
        size_t idx = (size_t)(b * 1024 + n) * 512 + h * 64 + d;
        ushort_t hi = f2bf(f);
        obh[idx] = hi;
        obl[idx] = f2bf(f - bf2f(hi));
      }
  }
}

// ---------------- launcher ----------------
extern "C" void kernel_launch(void* const* d_in, const int* in_sizes, int n_in,
                              void* d_out, int out_size, void* d_ws, size_t ws_size,
                              hipStream_t stream) {
  const float* cur = (const float*)d_in[0];   // [8,1024,512] fp32
  const float* hid = (const float*)d_in[1];   // [8,1024,512] fp32
  const float* Wq  = (const float*)d_in[2];   // [512,512]
  const float* Wkv = (const float*)d_in[3];   // [512,1024]
  const float* Wo  = (const float*)d_in[4];   // [512,512]

  ushort_t* ws = (ushort_t*)d_ws;
  ushort_t* Ah = ws;                    // 4,194,304  (hid split; reused: cur split; aout hi)
  ushort_t* Al = Ah + 4194304;          // 4,194,304  (… aout lo)
  ushort_t* kh = Al + 4194304;          // 4,194,304
  ushort_t* kl = kh + 4194304;          // 4,194,304
  ushort_t* vt = kl + 4194304;          // 4,194,304
  ushort_t* qhb = vt + 4194304;         // 4,194,304
  ushort_t* qlb = qhb + 4194304;        // 4,194,304
  ushort_t* WqTh = qlb + 4194304;       // 262,144
  ushort_t* WqTl = WqTh + 262144;       // 262,144
  ushort_t* WkvTh = WqTl + 262144;      // 524,288
  ushort_t* WkvTl = WkvTh + 524288;     // 524,288
  ushort_t* WoTh = WkvTl + 524288;      // 262,144
  ushort_t* WoTl = WoTh + 262144;       // 262,144

  dim3 tb(32, 8);
  transpose_split<<<dim3(16, 16), tb, 0, stream>>>(Wq, WqTh, WqTl, 512, 512);
  transpose_split<<<dim3(32, 16), tb, 0, stream>>>(Wkv, WkvTh, WkvTl, 512, 1024);
  transpose_split<<<dim3(16, 16), tb, 0, stream>>>(Wo, WoTh, WoTl, 512, 512);

  // kv projection (BN=128): 512 blocks
  split8<<<2048, 256, 0, stream>>>(hid, Ah, Al, 4194304 / 8);
  gemm3_bt<1, 4><<<dim3(8, 64), 256, 0, stream>>>(Ah, Al, WkvTh, WkvTl,
                                                  kh, kl, vt, (float*)nullptr, 512, 0);
  // q projection (BN=128): 256 blocks
  split8<<<2048, 256, 0, stream>>>(cur, Ah, Al, 4194304 / 8);
  gemm3_bt<0, 4><<<dim3(4, 64), 256, 0, stream>>>(Ah, Al, WqTh, WqTl,
                                                  qhb, qlb, (ushort_t*)nullptr, (float*)nullptr, 512, 0);
  // attention (A-region reused for aout hi/lo)
  flash_attn<<<512, 256, 0, stream>>>(qhb, qlb, kh, kl, vt, Ah, Al);
  // output projection (BN=128) -> fp32 d_out: 256 blocks
  gemm3_bt<2, 4><<<dim3(4, 64), 256, 0, stream>>>(Ah, Al, WoTh, WoTl,
                                                  (ushort_t*)nullptr, (ushort_t*)nullptr,
                                                  (ushort_t*)nullptr, (float*)d_out, 512, 512);
}

// Round 11
// 243.683 us; speedup vs baseline: 1.4415x; 1.0759x over previous
//
#include <hip/hip_runtime.h>

typedef unsigned short ushort_t;
typedef __attribute__((ext_vector_type(8))) short short8;
typedef __attribute__((ext_vector_type(4))) float f32x4;
typedef __attribute__((ext_vector_type(2))) unsigned uint2v;
typedef __attribute__((ext_vector_type(4))) unsigned uint4v;

#define LOG2E 1.44269504088896f

// async global->LDS, 16B per lane. LDS dest must be wave-uniform base + lane*16.
__device__ __forceinline__ void async16(const void* g, void* l) {
  __builtin_amdgcn_global_load_lds(
      (const __attribute__((address_space(1))) void*)g,
      (__attribute__((address_space(3))) void*)l, 16, 0, 0);
}

__device__ __forceinline__ ushort_t f2bf(float f) {
  union { float f; unsigned u; } x; x.f = f;
  unsigned u = x.u;
  u += 0x7fffu + ((u >> 16) & 1u);
  return (ushort_t)(u >> 16);
}

__device__ __forceinline__ float bf2f(ushort_t w) {
  union { unsigned u; float f; } x; x.u = ((unsigned)w) << 16;
  return x.f;
}

__device__ __forceinline__ short8 u4s8(uint4v u) { union { uint4v a; short8 b; } c; c.a = u; return c.b; }
__device__ __forceinline__ uint4v s8u4(short8 s) { union { short8 a; uint4v b; } c; c.a = s; return c.b; }
__device__ __forceinline__ unsigned fu(float f) { union { float a; unsigned b; } c; c.a = f; return c.b; }

// ------------- merged split ingest: cur+hid fp32 -> (hi, lo) bf16 -------------
__global__ __launch_bounds__(256) void split_all(const float* __restrict__ cur,
                                                 const float* __restrict__ hid,
                                                 ushort_t* __restrict__ ch,
                                                 ushort_t* __restrict__ cl,
                                                 ushort_t* __restrict__ hh,
                                                 ushort_t* __restrict__ hl) {
  int i = blockIdx.x * 256 + threadIdx.x;       // 0 .. 2*524288-1
  const float* src;
  ushort_t *hi, *lo;
  int j;
  if (i < 524288) { src = cur; hi = ch; lo = cl; j = i; }
  else            { src = hid; hi = hh; lo = hl; j = i - 524288; }
  const f32x4* s = (const f32x4*)src;
  f32x4 a = s[j * 2], b = s[j * 2 + 1];
  short8 oh, ol;
  #pragma unroll
  for (int k = 0; k < 4; k++) {
    ushort_t h = f2bf(a[k]); oh[k] = (short)h; ol[k] = (short)f2bf(a[k] - bf2f(h));
    h = f2bf(b[k]); oh[k + 4] = (short)h; ol[k + 4] = (short)f2bf(b[k] - bf2f(h));
  }
  ((short8*)hi)[j] = oh;
  ((short8*)lo)[j] = ol;
}

// ------- merged weight transpose+split: 3 matrices in one launch -------
__global__ __launch_bounds__(256) void transpose_all(const float* __restrict__ Wq,
                                                     const float* __restrict__ Wkv,
                                                     const float* __restrict__ Wo,
                                                     ushort_t* __restrict__ qh, ushort_t* __restrict__ ql,
                                                     ushort_t* __restrict__ kvh, ushort_t* __restrict__ kvl,
                                                     ushort_t* __restrict__ oh, ushort_t* __restrict__ ol) {
  __shared__ float tile[32][33];
  int bid = blockIdx.x;
  const float* src; ushort_t *dh, *dl; int Nn, bx, by;
  const int K = 512;
  if (bid < 256)      { src = Wq;  dh = qh;  dl = ql;  Nn = 512;  bx = (bid & 15) * 32; by = (bid >> 4) * 32; }
  else if (bid < 768) { int b = bid - 256; src = Wkv; dh = kvh; dl = kvl; Nn = 1024; bx = (b & 31) * 32; by = (b >> 5) * 32; }
  else                { int b = bid - 768; src = Wo;  dh = oh;  dl = ol;  Nn = 512;  bx = (b & 15) * 32; by = (b >> 4) * 32; }
  int tx = threadIdx.x & 31, ty = threadIdx.x >> 5;   // (32, 8)
  #pragma unroll
  for (int i = 0; i < 32; i += 8)
    tile[ty + i][tx] = src[(size_t)(by + ty + i) * Nn + bx + tx];
  __syncthreads();
  #pragma unroll
  for (int i = 0; i < 32; i += 8) {
    float v = tile[tx][ty + i];
    ushort_t h = f2bf(v);
    size_t idx = (size_t)(bx + ty + i) * K + by + tx;
    dh[idx] = h;
    dl[idx] = f2bf(v - bf2f(h));
  }
}

// ---- split GEMM: C = (Ah+Al)[M][K] @ (Bh+Bl)[Nn][K]^T, 3-product bf16x3 ----
// BM = MT*32, BN = TN*32. 4 waves (2x2); wave tile = (MT*16) x (TN*16).
// EPI 0: C -> (o_hi,o_lo) q-layout [B*H][N][D]
// EPI 1: col<512 -> (o_hi,o_lo) k-layout; col>=512 -> o_vt bf16 [B*H][D][N]
// EPI 2: outf fp32 row-major [M][ldo]  (final output)
template<int EPI, int MT, int TN>
__global__ __launch_bounds__(256) void gemm3_bt(const ushort_t* __restrict__ Ah,
                                                const ushort_t* __restrict__ Al,
                                                const ushort_t* __restrict__ Bh,
                                                const ushort_t* __restrict__ Bl,
                                                ushort_t* __restrict__ o_hi,
                                                ushort_t* __restrict__ o_lo,
                                                ushort_t* __restrict__ o_vt,
                                                float* __restrict__ outf,
                                                int K, int ldo) {
  constexpr int BM = MT * 32;
  constexpr int BN = TN * 32;
  __shared__ __align__(16) ushort_t Ash[BM * 32];
  __shared__ __align__(16) ushort_t Asl[BM * 32];
  __shared__ __align__(16) ushort_t Bsh[BN * 32];
  __shared__ __align__(16) ushort_t Bsl[BN * 32];
  const int tid = threadIdx.x;
  const int wave = tid >> 6, lane = tid & 63;
  const int wm = (wave >> 1) * (MT * 16), wn = (wave & 1) * (TN * 16);
  const int m0 = blockIdx.y * BM, n0 = blockIdx.x * BN;
  const int lrow = lane & 15, lq = lane >> 4;

  f32x4 acc[MT][TN];
  const f32x4 z = {0.f, 0.f, 0.f, 0.f};
  #pragma unroll
  for (int i = 0; i < MT; i++)
    #pragma unroll
    for (int j = 0; j < TN; j++) acc[i][j] = z;

  for (int k0 = 0; k0 < K; k0 += 32) {
    __syncthreads();
    #pragma unroll
    for (int i = 0; i < MT / 2; i++) {   // A tile: BM rows x 4 chunks
      int g = i * 256 + tid;
      int r = g >> 2, kc = g & 3;
      size_t ga = (size_t)(m0 + r) * K + k0 + kc * 8;
      async16(&Ah[ga], &Ash[g * 8]);
      async16(&Al[ga], &Asl[g * 8]);
    }
    #pragma unroll
    for (int i = 0; i < TN / 2; i++) {   // B tile: BN rows x 4 chunks
      int g = i * 256 + tid;
      int r = g >> 2, kc = g & 3;
      size_t gb = (size_t)(n0 + r) * K + k0 + kc * 8;
      async16(&Bh[gb], &Bsh[g * 8]);
      async16(&Bl[gb], &Bsl[g * 8]);
    }
    __syncthreads();  // drains vmcnt(0): all tiles landed

    short8 afh[MT], bfr[TN];
    #pragma unroll
    for (int t = 0; t < MT; t++)
      afh[t] = *(const short8*)&Ash[(wm + t * 16 + lrow) * 32 + lq * 8];
    #pragma unroll
    for (int t = 0; t < TN; t++)
      bfr[t] = *(const short8*)&Bsh[(wn + t * 16 + lrow) * 32 + lq * 8];
    #pragma unroll
    for (int ti = 0; ti < MT; ti++)
      #pragma unroll
      for (int tj = 0; tj < TN; tj++)
        acc[ti][tj] = __builtin_amdgcn_mfma_f32_16x16x32_bf16(afh[ti], bfr[tj], acc[ti][tj], 0, 0, 0);

    {
      short8 afl[MT];
      #pragma unroll
      for (int t = 0; t < MT; t++)
        afl[t] = *(const short8*)&Asl[(wm + t * 16 + lrow) * 32 + lq * 8];
      #pragma unroll
      for (int ti = 0; ti < MT; ti++)
        #pragma unroll
        for (int tj = 0; tj < TN; tj++)
          acc[ti][tj] = __builtin_amdgcn_mfma_f32_16x16x32_bf16(afl[ti], bfr[tj], acc[ti][tj], 0, 0, 0);
    }
    #pragma unroll
    for (int t = 0; t < TN; t++)
      bfr[t] = *(const short8*)&Bsl[(wn + t * 16 + lrow) * 32 + lq * 8];
    #pragma unroll
    for (int ti = 0; ti < MT; ti++)
      #pragma unroll
      for (int tj = 0; tj < TN; tj++)
        acc[ti][tj] = __builtin_amdgcn_mfma_f32_16x16x32_bf16(afh[ti], bfr[tj], acc[ti][tj], 0, 0, 0);
  }

  // epilogue
  #pragma unroll
  for (int ti = 0; ti < MT; ti++) {
    #pragma unroll
    for (int tj = 0; tj < TN; tj++) {
      int row0 = m0 + wm + ti * 16 + lq * 4;
      int col = n0 + wn + tj * 16 + lrow;
      #pragma unroll
      for (int r = 0; r < 4; r++) {
        int m = row0 + r;
        float fv = acc[ti][tj][r];
        if (EPI == 0) {
          size_t idx = (size_t)((m >> 10) * 8 + (col >> 6)) * 65536 + (m & 1023) * 64 + (col & 63);
          ushort_t h = f2bf(fv);
          o_hi[idx] = h;
          o_lo[idx] = f2bf(fv - bf2f(h));
        } else if (EPI == 1) {
          if (col < 512) {
            size_t idx = (size_t)((m >> 10) * 8 + (col >> 6)) * 65536 + (m & 1023) * 64 + (col & 63);
            ushort_t h = f2bf(fv);
            o_hi[idx] = h;
            o_lo[idx] = f2bf(fv - bf2f(h));
          } else {
            int cc = col - 512;
            o_vt[(size_t)(((m >> 10) * 8 + (cc >> 6)) * 64 + (cc & 63)) * 1024 + (m & 1023)] = f2bf(fv);
          }
        } else {
          outf[(size_t)m * ldo + col] = fv;   // fp32 final output
        }
      }
    }
  }
}

// ---------------- flash attention v3 (unchanged from round 10) ----------------
__global__ __launch_bounds__(256) void flash_attn(const ushort_t* __restrict__ qh,
                                                  const ushort_t* __restrict__ ql,
                                                  const ushort_t* __restrict__ kh,
                                                  const ushort_t* __restrict__ kl,
                                                  const ushort_t* __restrict__ vtb,
                                                  ushort_t* __restrict__ obh,
                                                  ushort_t* __restrict__ obl) {
  constexpr int KW = 34;   // K/V row stride (dwords)
  constexpr int SWS = 36;  // Sw row stride (dwords)
  constexpr int PWS = 36;  // Pw row stride (dwords)
  __shared__ __align__(16) unsigned Ksh[64 * KW];
  __shared__ __align__(16) unsigned Ksl[64 * KW];
  __shared__ __align__(16) unsigned VTs[64 * KW];
  __shared__ __align__(16) float Sw[4][64 * SWS];     // per wave: S^T [col][row]
  __shared__ __align__(16) unsigned Pw[4][32 * PWS];  // per wave: P [row][col/2]

  const int tid = threadIdx.x;
  const int wave = tid >> 6, lane = tid & 63;
  const int bh = blockIdx.x >> 3, qt = blockIdx.x & 7;
  const int lrow = lane & 15, lq = lane >> 4;

  const ushort_t* Qh = qh + (size_t)bh * 65536;
  const ushort_t* Ql = ql + (size_t)bh * 65536;
  const ushort_t* Kph = kh + (size_t)bh * 65536;
  const ushort_t* Kpl = kl + (size_t)bh * 65536;
  const ushort_t* VT = vtb + (size_t)bh * 65536;

  const int qrow0 = qt * 128 + wave * 32;

  short8 qfh[2][2], qfl[2][2];
  #pragma unroll
  for (int mt = 0; mt < 2; mt++)
    #pragma unroll
    for (int s = 0; s < 2; s++) {
      size_t idx = (size_t)(qrow0 + mt * 16 + lrow) * 64 + s * 32 + lq * 8;
      qfh[mt][s] = *(const short8*)&Qh[idx];
      qfl[mt][s] = *(const short8*)&Ql[idx];
    }

  const f32x4 z = {0.f, 0.f, 0.f, 0.f};
  f32x4 oacc[2][4];
  #pragma unroll
  for (int mt = 0; mt < 2; mt++)
    #pragma unroll
    for (int dt = 0; dt < 4; dt++) oacc[mt][dt] = z;

  float m_i = -1e30f, l_i = 0.f;          // per row-owner lane (r = lane>>1)
  const int r = lane >> 1, hlf = lane & 1;

  for (int kt = 0; kt < 16; kt++) {
    short8 skh[2], skl[2], sv[2];
    #pragma unroll
    for (int i = 0; i < 2; i++) {
      int g = i * 256 + tid;      // 0..511
      int rw = g >> 3, ch = g & 7;
      size_t kidx = (size_t)(kt * 64 + rw) * 64 + ch * 8;
      skh[i] = *(const short8*)&Kph[kidx];
      skl[i] = *(const short8*)&Kpl[kidx];
      sv[i]  = *(const short8*)&VT[(size_t)rw * 1024 + kt * 64 + ch * 8];
    }
    __syncthreads();
    #pragma unroll
    for (int i = 0; i < 2; i++) {
      int g = i * 256 + tid;
      int rw = g >> 3, ch = g & 7;
      int l = rw * KW + ch * 4;
      uint4v a = s8u4(skh[i]);
      *(uint2v*)&Ksh[l] = (uint2v){a.x, a.y};
      *(uint2v*)&Ksh[l + 2] = (uint2v){a.z, a.w};
      a = s8u4(skl[i]);
      *(uint2v*)&Ksl[l] = (uint2v){a.x, a.y};
      *(uint2v*)&Ksl[l + 2] = (uint2v){a.z, a.w};
      a = s8u4(sv[i]);
      *(uint2v*)&VTs[l] = (uint2v){a.x, a.y};
      *(uint2v*)&VTs[l + 2] = (uint2v){a.z, a.w};
    }
    __syncthreads();

    f32x4 sacc[2][4];
    #pragma unroll
    for (int mt = 0; mt < 2; mt++)
      #pragma unroll
      for (int nt = 0; nt < 4; nt++) sacc[mt][nt] = z;
    #pragma unroll
    for (int s = 0; s < 2; s++) {
      short8 bfr[4];
      #pragma unroll
      for (int nt = 0; nt < 4; nt++) {
        int base = (nt * 16 + lrow) * KW + s * 16 + lq * 4;
        uint2v a = *(const uint2v*)&Ksh[base];
        uint2v b = *(const uint2v*)&Ksh[base + 2];
        bfr[nt] = u4s8((uint4v){a.x, a.y, b.x, b.y});
      }
      #pragma unroll
      for (int mt = 0; mt < 2; mt++)
        #pragma unroll
        for (int nt = 0; nt < 4; nt++) {
          sacc[mt][nt] = __builtin_amdgcn_mfma_f32_16x16x32_bf16(qfh[mt][s], bfr[nt], sacc[mt][nt], 0, 0, 0);
          sacc[mt][nt] = __builtin_amdgcn_mfma_f32_16x16x32_bf16(qfl[mt][s], bfr[nt], sacc[mt][nt], 0, 0, 0);
        }
      #pragma unroll
      for (int nt = 0; nt < 4; nt++) {
        int base = (nt * 16 + lrow) * KW + s * 16 + lq * 4;
        uint2v a = *(const uint2v*)&Ksl[base];
        uint2v b = *(const uint2v*)&Ksl[base + 2];
        bfr[nt] = u4s8((uint4v){a.x, a.y, b.x, b.y});
      }
      #pragma unroll
      for (int mt = 0; mt < 2; mt++)
        #pragma unroll
        for (int nt = 0; nt < 4; nt++)
          sacc[mt][nt] = __builtin_amdgcn_mfma_f32_16x16x32_bf16(qfh[mt][s], bfr[nt], sacc[mt][nt], 0, 0, 0);
    }

    #pragma unroll
    for (int mt = 0; mt < 2; mt++)
      #pragma unroll
      for (int nt = 0; nt < 4; nt++)
        *(f32x4*)&Sw[wave][(nt * 16 + lrow) * SWS + mt * 16 + lq * 4] = sacc[mt][nt];

    float vals[32];
    float mx = -1e30f;
    #pragma unroll
    for (int j = 0; j < 32; j++) {
      vals[j] = Sw[wave][(hlf * 32 + j) * SWS + r];
      mx = fmaxf(mx, vals[j]);
    }
    mx = fmaxf(mx, __shfl_xor(mx, 1));
    float mnew = fmaxf(m_i, mx);
    float alpha = exp2f((m_i - mnew) * LOG2E);
    float sum = 0.f;
    #pragma unroll
    for (int j8 = 0; j8 < 4; j8++) {
      uint4v pk;
      #pragma unroll
      for (int q = 0; q < 4; q++) {
        float p0 = exp2f((vals[j8 * 8 + 2 * q] - mnew) * LOG2E);
        float p1 = exp2f((vals[j8 * 8 + 2 * q + 1] - mnew) * LOG2E);
        sum += p0 + p1;
        pk[q] = __builtin_amdgcn_perm(fu(p1), fu(p0), 0x07060302u);
      }
      *(uint4v*)&Pw[wave][r * PWS + hlf * 16 + j8 * 4] = pk;
    }
    sum += __shfl_xor(sum, 1);
    l_i = l_i * alpha + sum;
    m_i = mnew;

    f32x4 al[2];
    #pragma unroll
    for (int mt = 0; mt < 2; mt++)
      #pragma unroll
      for (int e = 0; e < 4; e++)
        al[mt][e] = __shfl(alpha, (mt * 16 + lq * 4 + e) * 2);
    #pragma unroll
    for (int mt = 0; mt < 2; mt++)
      #pragma unroll
      for (int dt = 0; dt < 4; dt++)
        #pragma unroll
        for (int e = 0; e < 4; e++) oacc[mt][dt][e] *= al[mt][e];

    #pragma unroll
    for (int s = 0; s < 2; s++) {
      short8 pf[2], vf[4];
      #pragma unroll
      for (int mt = 0; mt < 2; mt++)
        pf[mt] = u4s8(*(const uint4v*)&Pw[wave][(mt * 16 + lrow) * PWS + s * 16 + lq * 4]);
      #pragma unroll
      for (int dt = 0; dt < 4; dt++) {
        int base = (dt * 16 + lrow) * KW + s * 16 + lq * 4;
        uint2v a = *(const uint2v*)&VTs[base];
        uint2v b = *(const uint2v*)&VTs[base + 2];
        vf[dt] = u4s8((uint4v){a.x, a.y, b.x, b.y});
      }
      #pragma unroll
      for (int mt = 0; mt < 2; mt++)
        #pragma unroll
        for (int dt = 0; dt < 4; dt++)
          oacc[mt][dt] = __builtin_amdgcn_mfma_f32_16x16x32_bf16(pf[mt], vf[dt], oacc[mt][dt], 0, 0, 0);
    }
  }

  const int b = bh >> 3, h = bh & 7;
  #pragma unroll
  for (int mt = 0; mt < 2; mt++) {
    f32x4 li;
    #pragma unroll
    for (int e = 0; e < 4; e++)
      li[e] = __shfl(l_i, (mt * 16 + lq * 4 + e) * 2);
    #pragma unroll
    for (int dt = 0; dt < 4; dt++)
      #pragma unroll
      for (int e = 0; e < 4; e++) {
        int n = qrow0 + mt * 16 + lq * 4 + e;
        int d = dt * 16 + lrow;
        float f = oacc[mt][dt][e] / li[e];
        size_t idx = (size_t)(b * 1024 + n) * 512 + h * 64 + d;
        ushort_t hi = f2bf(f);
        obh[idx] = hi;
        obl[idx] = f2bf(f - bf2f(hi));
      }
  }
}

// ---------------- launcher ----------------
extern "C" void kernel_launch(void* const* d_in, const int* in_sizes, int n_in,
                              void* d_out, int out_size, void* d_ws, size_t ws_size,
                              hipStream_t stream) {
  const float* cur = (const float*)d_in[0];   // [8,1024,512] fp32
  const float* hid = (const float*)d_in[1];   // [8,1024,512] fp32
  const float* Wq  = (const float*)d_in[2];   // [512,512]
  const float* Wkv = (const float*)d_in[3];   // [512,1024]
  const float* Wo  = (const float*)d_in[4];   // [512,512]

  ushort_t* ws = (ushort_t*)d_ws;
  ushort_t* Ch = ws;                    // 4,194,304  (cur split; reused: aout hi)
  ushort_t* Cl = Ch + 4194304;          // 4,194,304  (cur split; reused: aout lo)
  ushort_t* Hh = Cl + 4194304;          // 4,194,304  (hid split)
  ushort_t* Hl = Hh + 4194304;          // 4,194,304
  ushort_t* kh = Hl + 4194304;          // 4,194,304
  ushort_t* kl = kh + 4194304;          // 4,194,304
  ushort_t* vt = kl + 4194304;          // 4,194,304
  ushort_t* qhb = vt + 4194304;         // 4,194,304
  ushort_t* qlb = qhb + 4194304;        // 4,194,304
  ushort_t* WqTh = qlb + 4194304;       // 262,144
  ushort_t* WqTl = WqTh + 262144;       // 262,144
  ushort_t* WkvTh = WqTl + 262144;      // 524,288
  ushort_t* WkvTl = WkvTh + 524288;     // 524,288
  ushort_t* WoTh = WkvTl + 524288;      // 262,144
  ushort_t* WoTl = WoTh + 262144;       // 262,144

  transpose_all<<<1024, 256, 0, stream>>>(Wq, Wkv, Wo, WqTh, WqTl, WkvTh, WkvTl, WoTh, WoTl);
  split_all<<<4096, 256, 0, stream>>>(cur, hid, Ch, Cl, Hh, Hl);

  // kv projection: BM=64, BN=128 -> grid (8,128) = 1024 blocks (4/CU)
  gemm3_bt<1, 2, 4><<<dim3(8, 128), 256, 0, stream>>>(Hh, Hl, WkvTh, WkvTl,
                                                      kh, kl, vt, (float*)nullptr, 512, 0);
  // q projection: BM=64, BN=128 -> grid (4,128) = 512 blocks (2/CU)
  gemm3_bt<0, 2, 4><<<dim3(4, 128), 256, 0, stream>>>(Ch, Cl, WqTh, WqTl,
                                                      qhb, qlb, (ushort_t*)nullptr, (float*)nullptr, 512, 0);
  // attention (Ch/Cl reused for aout hi/lo; cur split dead after q-proj)
  flash_attn<<<512, 256, 0, stream>>>(qhb, qlb, kh, kl, vt, Ch, Cl);
  // output projection: BM=64, BN=128 -> grid (4,128) = 512 blocks -> fp32 d_out
  gemm3_bt<2, 2, 4><<<dim3(4, 128), 256, 0, stream>>>(Ch, Cl, WoTh, WoTl,
                                                      (ushort_t*)nullptr, (ushort_t*)nullptr,
                                                      (ushort_t*)nullptr, (float*)d_out, 512, 512);
}